// Round 6
// baseline (1070.285 us; speedup 1.0000x reference)
//
#include <hip/hip_runtime.h>

#define HID 50
#define FOURH 200
#define TSTEPS 2048
#define NBATCH 1024

#define LOG2E 1.44269504f

typedef _Float16 v2h __attribute__((ext_vector_type(2)));

__device__ __forceinline__ float frcp(float x)  { return __builtin_amdgcn_rcpf(x); }
__device__ __forceinline__ float fexp2(float x) { return __builtin_amdgcn_exp2f(x); }
__device__ __forceinline__ v2h bc_v2h(unsigned int u) {
    return __builtin_bit_cast(v2h, u);
}

// 2 waves per batch, ONE barrier per step, NO LDS h-broadcast (r5 post-mortem:
// its 2 barriers + hbuf round-trip cost ~350 cy/step). Wave0 owns gates {i,f},
// wave1 owns {g,o} (50 fdot2/wave). Both waves hold bit-identical h in
// registers after the redundant tail, so each broadcasts h from its OWN regs
// via DPP row_shl:1 + pack + 25 v_readlane -> SGPR operands for fdot2 (r2
// path). The only cross-wave traffic is one float2 LDS exchange of the two
// activated gate values, parity-double-buffered so a single barrier per step
// suffices (write[t&1] -> barrier -> read[t&1]; next write goes to [t&1^1]).
// Folds: sigmoid sign (-log2e) and tanh 2x (+2log2e) in weight scales; bias+x
// in dot-chain inits; g-output scaled by 2log2e (gg2L = fma(-4L,s,2L)) so the
// cell state lives in 2L-space and tanh(c) needs no pre-multiply.
__global__ __launch_bounds__(128, 1)
void lstm_2wave_rl_kernel(const float* __restrict__ x,
                          const float* __restrict__ Wx,
                          const float* __restrict__ Wh,
                          const float* __restrict__ bias,
                          const float* __restrict__ Wd,
                          const float* __restrict__ bd,
                          float* __restrict__ out) {
    const int b    = blockIdx.x;
    const int tid  = threadIdx.x;
    const int wv   = tid >> 6;          // 0 or 1
    const int lane = tid & 63;
    const int lc   = (lane < HID) ? lane : (HID - 1);

    __shared__ __align__(16) float  xs[TSTEPS + 4];
    __shared__ __align__(16) float2 exch[2][2][64];   // [parity][wave][lane]

    // Stage x (coalesced float4 loads, 128 threads).
    const float4* xb4 = (const float4*)(x + (size_t)b * TSTEPS);
    float4* xs4 = (float4*)xs;
    #pragma unroll
    for (int i = tid; i < TSTEPS / 4; i += 128) xs4[i] = xb4[i];
    if (tid == 0) xs[TSTEPS] = 0.0f;

    // Gate columns: wave0 -> A=i, B=f ; wave1 -> A=g, B=o.
    const int   colA = (wv == 0) ? lc : (2 * HID + lc);
    const int   colB = (wv == 0) ? (HID + lc) : (3 * HID + lc);
    const float scA  = (wv == 0) ? -LOG2E : (2.0f * LOG2E);  // sigmoid / tanh form
    const float scB  = -LOG2E;                               // f, o sigmoids
    // actA = fma(mA, s, aAc): wave0 ig = s ; wave1 gg2L = 2L - 4L*s
    const float mA   = (wv == 0) ? 1.0f : (-4.0f * LOG2E);
    const float aAc  = (wv == 0) ? 0.0f : (2.0f * LOG2E);

    // Recurrent weights for my 2 gates, packed along k as half2 (25 pairs).
    v2h wA[25], wB[25];
    #pragma unroll
    for (int p = 0; p < 25; ++p) {
        const float* r0 = Wh + (2 * p) * FOURH;
        const float* r1 = Wh + (2 * p + 1) * FOURH;
        wA[p] = v2h{(_Float16)(scA * r0[colA]), (_Float16)(scA * r1[colA])};
        wB[p] = v2h{(_Float16)(scB * r0[colB]), (_Float16)(scB * r1[colB])};
    }
    const float wxA = scA * Wx[colA], bsA = scA * bias[colA];
    const float wxB = scB * Wx[colB], bsB = scB * bias[colB];

    float cs = 0.0f;   // 2L-scaled cell state
    float h  = 0.0f;
    __syncthreads();   // staging visible

    float xt = xs[0];

    for (int t = 0; t < TSTEPS; ++t) {
        const float xt_next = xs[t + 1];

        // Broadcast own h (both waves hold identical h): f16 pack + readlane.
        const unsigned h16  = (unsigned)__builtin_bit_cast(unsigned short, (_Float16)h);
        const unsigned h16n = (unsigned)__builtin_amdgcn_update_dpp(
            0, (int)h16, 0x101 /*row_shl:1*/, 0xf, 0xf, true);
        const unsigned hp = h16 | (h16n << 16);
        unsigned sh[25];
        #pragma unroll
        for (int k = 0; k < 25; ++k)
            sh[k] = (unsigned)__builtin_amdgcn_readlane((int)hp, 2 * k);

        // 4 independent dot2 chains (2 per gate); bias+x folded into inits.
        float aA0 = fmaf(xt, wxA, bsA), aA1 = 0.f;
        float aB0 = fmaf(xt, wxB, bsB), aB1 = 0.f;
        #pragma unroll
        for (int j = 0; j < 12; ++j) {
            const v2h h0 = bc_v2h(sh[2 * j]);
            const v2h h1 = bc_v2h(sh[2 * j + 1]);
            aA0 = __builtin_amdgcn_fdot2(wA[2 * j],     h0, aA0, false);
            aB0 = __builtin_amdgcn_fdot2(wB[2 * j],     h0, aB0, false);
            aA1 = __builtin_amdgcn_fdot2(wA[2 * j + 1], h1, aA1, false);
            aB1 = __builtin_amdgcn_fdot2(wB[2 * j + 1], h1, aB1, false);
        }
        {   // pair 24 (h48,h49)
            const v2h hp24 = bc_v2h(sh[24]);
            aA0 = __builtin_amdgcn_fdot2(wA[24], hp24, aA0, false);
            aB0 = __builtin_amdgcn_fdot2(wB[24], hp24, aB0, false);
        }
        const float zA = aA0 + aA1;
        const float zB = aB0 + aB1;

        const float sA   = frcp(1.0f + fexp2(zA));
        const float actA = fmaf(mA, sA, aAc);          // wave0: ig ; wave1: gg2L
        const float actB = frcp(1.0f + fexp2(zB));     // wave0: fg ; wave1: og

        exch[t & 1][wv][lane] = make_float2(actA, actB);
        __syncthreads();
        const float2 pr = exch[t & 1][wv ^ 1][lane];

        // prod2L = ig * gg2L identical on both waves (commutative).
        const float prod = actA * pr.x;
        const float fgv  = (wv == 0) ? actB : pr.y;
        const float ogv  = (wv == 0) ? pr.y : actB;

        cs = fmaf(fgv, cs, prod);                              // 2L * c
        const float tc = fmaf(-2.0f, frcp(1.0f + fexp2(cs)), 1.0f);  // tanh(c)
        h = ogv * tc;

        xt = xt_next;
    }

    // out[b] = h_T . Wd + bd  (wave0 reduces; h identical on both waves)
    if (wv == 0) {
        float v = (lane < HID) ? h * Wd[lane] : 0.0f;
        #pragma unroll
        for (int off = 32; off > 0; off >>= 1) v += __shfl_down(v, off);
        if (lane == 0) out[b] = v + bd[0];
    }
}

extern "C" void kernel_launch(void* const* d_in, const int* in_sizes, int n_in,
                              void* d_out, int out_size, void* d_ws, size_t ws_size,
                              hipStream_t stream) {
    const float* x    = (const float*)d_in[0];  // [1024, 2048, 1]
    const float* Wx   = (const float*)d_in[1];  // [1, 200]
    const float* Wh   = (const float*)d_in[2];  // [50, 200]
    const float* bias = (const float*)d_in[3];  // [200]
    const float* Wd   = (const float*)d_in[4];  // [50, 1]
    const float* bd   = (const float*)d_in[5];  // [1]
    float* out = (float*)d_out;                 // [1024, 1]

    lstm_2wave_rl_kernel<<<dim3(NBATCH), dim3(128), 0, stream>>>(
        x, Wx, Wh, bias, Wd, bd, out);
}

// Round 7
// 701.405 us; speedup vs baseline: 1.5259x; 1.5259x over previous
//
#include <hip/hip_runtime.h>

#define HID 50
#define FOURH 200
#define TSTEPS 2048
#define NBATCH 1024

#define LOG2E 1.44269504f

typedef _Float16 v2h __attribute__((ext_vector_type(2)));

__device__ __forceinline__ float frcp(float x)  { return __builtin_amdgcn_rcpf(x); }
__device__ __forceinline__ float fexp2(float x) { return __builtin_amdgcn_exp2f(x); }
__device__ __forceinline__ v2h bc_v2h(unsigned int u) {
    return __builtin_bit_cast(v2h, u);
}

// Single wave per batch (multi-wave killed: r5/r6 hit the >=700us gate, both
// poisoned by weight-parking at VGPR=40). Issue-cadence model: lone wave
// issues 1 VALU op / 4 cy, dur ~= inst_per_step * 4cy (fits r0/r2/r3/r5/r6).
// So: minimize instructions per step.
//   - h broadcast from registers: cvt f16 + DPP row_shl:1 + pack + 25
//     v_readlane -> SGPR operands for fdot2 (r2-proven, no LDS round-trip).
//   - bias+x folded into dot-chain initializers (saves 4 adds/step).
//   - sigmoid sign (-L) folded into i/f/o weights: s = rcp(1+exp2(z_s)).
//   - cell kept in 2L-space: g weights scaled +2L, gg2L = 2L - 4L*s,
//     cs = fma(fg, cs, ig*gg2L), tanh(c) = fma(-2, rcp(1+exp2(cs)), 1)
//     -> no pre-multiply in the serial tail.
//   - unroll 4: loop arithmetic amortized.
// ~160 inst/step vs r2's ~182 -> predict ~640-680 cy/step.
__global__ __launch_bounds__(64, 1)
void lstm_trim_kernel(const float* __restrict__ x,
                      const float* __restrict__ Wx,
                      const float* __restrict__ Wh,
                      const float* __restrict__ bias,
                      const float* __restrict__ Wd,
                      const float* __restrict__ bd,
                      float* __restrict__ out) {
    const int b    = blockIdx.x;
    const int lane = threadIdx.x;
    const int lc   = (lane < HID) ? lane : (HID - 1);

    __shared__ __align__(16) float xs[TSTEPS + 4];

    // Stage x (coalesced float4 loads).
    const float4* xb4 = (const float4*)(x + (size_t)b * TSTEPS);
    float4* xs4 = (float4*)xs;
    #pragma unroll
    for (int i = lane; i < TSTEPS / 4; i += 64) xs4[i] = xb4[i];
    if (lane == 0) xs[TSTEPS] = 0.0f;

    // Recurrent weights packed along k as half2 (25 pairs), with activation
    // scales folded: i/f/o -> -L (sigmoid sign), g -> +2L (tanh form).
    const float SNEG = -LOG2E;
    const float S2L  = 2.0f * LOG2E;
    v2h wi[25], wf[25], wg[25], wo[25];
    #pragma unroll
    for (int k2 = 0; k2 < 25; ++k2) {
        const float* r0 = Wh + (2 * k2) * FOURH;
        const float* r1 = Wh + (2 * k2 + 1) * FOURH;
        wi[k2] = v2h{(_Float16)(SNEG * r0[lc]),           (_Float16)(SNEG * r1[lc])};
        wf[k2] = v2h{(_Float16)(SNEG * r0[HID + lc]),     (_Float16)(SNEG * r1[HID + lc])};
        wg[k2] = v2h{(_Float16)(S2L  * r0[2 * HID + lc]), (_Float16)(S2L  * r1[2 * HID + lc])};
        wo[k2] = v2h{(_Float16)(SNEG * r0[3 * HID + lc]), (_Float16)(SNEG * r1[3 * HID + lc])};
    }
    const float wx_i = SNEG * Wx[lc],           b_i = SNEG * bias[lc];
    const float wx_f = SNEG * Wx[HID + lc],     b_f = SNEG * bias[HID + lc];
    const float wx_g = S2L  * Wx[2 * HID + lc], b_g = S2L  * bias[2 * HID + lc];
    const float wx_o = SNEG * Wx[3 * HID + lc], b_o = SNEG * bias[3 * HID + lc];

    float cs = 0.0f;   // 2L-scaled cell state
    float h  = 0.0f;
    __syncthreads();   // x staging visible

    float xt = xs[0];

    #pragma unroll 4
    for (int t = 0; t < TSTEPS; ++t) {
        const float xt_next = xs[t + 1];

        // Broadcast h: f16 + neighbor via DPP + pack + 25 readlane -> SGPR.
        const unsigned h16  = (unsigned)__builtin_bit_cast(unsigned short, (_Float16)h);
        const unsigned h16n = (unsigned)__builtin_amdgcn_update_dpp(
            0, (int)h16, 0x101 /*row_shl:1*/, 0xf, 0xf, true);
        const unsigned hp = h16 | (h16n << 16);
        unsigned sh[25];
        #pragma unroll
        for (int k = 0; k < 25; ++k)
            sh[k] = (unsigned)__builtin_amdgcn_readlane((int)hp, 2 * k);

        // 8 independent dot2 chains (2 per gate); bias+x folded into inits.
        float ai0 = fmaf(xt, wx_i, b_i), ai1 = 0.f;
        float af0 = fmaf(xt, wx_f, b_f), af1 = 0.f;
        float ag0 = fmaf(xt, wx_g, b_g), ag1 = 0.f;
        float ao0 = fmaf(xt, wx_o, b_o), ao1 = 0.f;
        #pragma unroll
        for (int j = 0; j < 12; ++j) {
            const v2h h0 = bc_v2h(sh[2 * j]);
            const v2h h1 = bc_v2h(sh[2 * j + 1]);
            ai0 = __builtin_amdgcn_fdot2(wi[2 * j],     h0, ai0, false);
            af0 = __builtin_amdgcn_fdot2(wf[2 * j],     h0, af0, false);
            ag0 = __builtin_amdgcn_fdot2(wg[2 * j],     h0, ag0, false);
            ao0 = __builtin_amdgcn_fdot2(wo[2 * j],     h0, ao0, false);
            ai1 = __builtin_amdgcn_fdot2(wi[2 * j + 1], h1, ai1, false);
            af1 = __builtin_amdgcn_fdot2(wf[2 * j + 1], h1, af1, false);
            ag1 = __builtin_amdgcn_fdot2(wg[2 * j + 1], h1, ag1, false);
            ao1 = __builtin_amdgcn_fdot2(wo[2 * j + 1], h1, ao1, false);
        }
        {   // pair 24 (h48,h49)
            const v2h hp24 = bc_v2h(sh[24]);
            ai0 = __builtin_amdgcn_fdot2(wi[24], hp24, ai0, false);
            af0 = __builtin_amdgcn_fdot2(wf[24], hp24, af0, false);
            ag0 = __builtin_amdgcn_fdot2(wg[24], hp24, ag0, false);
            ao0 = __builtin_amdgcn_fdot2(wo[24], hp24, ao0, false);
        }
        const float zi = ai0 + ai1;   // = -L * z_i
        const float zf = af0 + af1;   // = -L * z_f
        const float zg = ag0 + ag1;   // = 2L * z_g
        const float zo = ao0 + ao1;   // = -L * z_o

        const float ig = frcp(1.0f + fexp2(zi));                  // sigmoid
        const float fg = frcp(1.0f + fexp2(zf));
        const float og = frcp(1.0f + fexp2(zo));
        const float sg = frcp(1.0f + fexp2(zg));
        const float gg2L = fmaf(-4.0f * LOG2E, sg, 2.0f * LOG2E); // 2L*tanh(z_g)

        cs = fmaf(fg, cs, ig * gg2L);                             // 2L * c
        const float tc = fmaf(-2.0f, frcp(1.0f + fexp2(cs)), 1.0f); // tanh(c)
        h = og * tc;

        xt = xt_next;
    }

    // out[b] = h_T . Wd + bd
    float v = (lane < HID) ? h * Wd[lane] : 0.0f;
    #pragma unroll
    for (int off = 32; off > 0; off >>= 1) v += __shfl_down(v, off);
    if (lane == 0) out[b] = v + bd[0];
}

extern "C" void kernel_launch(void* const* d_in, const int* in_sizes, int n_in,
                              void* d_out, int out_size, void* d_ws, size_t ws_size,
                              hipStream_t stream) {
    const float* x    = (const float*)d_in[0];  // [1024, 2048, 1]
    const float* Wx   = (const float*)d_in[1];  // [1, 200]
    const float* Wh   = (const float*)d_in[2];  // [50, 200]
    const float* bias = (const float*)d_in[3];  // [200]
    const float* Wd   = (const float*)d_in[4];  // [50, 1]
    const float* bd   = (const float*)d_in[5];  // [1]
    float* out = (float*)d_out;                 // [1024, 1]

    lstm_trim_kernel<<<dim3(NBATCH), dim3(64), 0, stream>>>(
        x, Wx, Wh, bias, Wd, bd, out);
}

// Round 10
// 686.858 us; speedup vs baseline: 1.5582x; 1.0212x over previous
//
#include <hip/hip_runtime.h>

#define HID 50
#define FOURH 200
#define TSTEPS 2048
#define NBATCH 1024

#define LOG2E 1.44269504f

typedef _Float16 v2h __attribute__((ext_vector_type(2)));

__device__ __forceinline__ float frcp(float x)  { return __builtin_amdgcn_rcpf(x); }
__device__ __forceinline__ float fexp2(float x) { return __builtin_amdgcn_exp2f(x); }
__device__ __forceinline__ v2h bc_v2h(unsigned int u) {
    return __builtin_bit_cast(v2h, u);
}

// Empirical law from r0..r7 counters: dur = VALU_inst x 4cy + idle (lone wave
// issues 1 inst / 4cy; VALUBusy == inst*4/dur). r7: 178 inst + 110cy idle
// (serial tail trans-latency, fully exposed after the dot block). int8 (r8)
// is dead: weight-quant error floor ~1e-3 > 9.5e-4 threshold. This round
// keeps r7's exact f16 math and attacks BOTH terms:
//  - PIPELINED GATE ORDER: i-dots -> sigmoid(i) issued UNDER g-dots ->
//    sg/gg2L/prod under f-dots -> fg/cs/exp2(cs)/rcp under o-dots -> og, h.
//    The tail's trans chain hides in the dot-issue shadow instead of idling.
//  - x read as float4 (1 ds_read_b128 / 4 steps, prefetched a block ahead).
//  - h broadcast from registers (r2 path): cvt f16 + DPP row_shl:1 + pack +
//    25 v_readlane -> SGPR operands for fdot2. No LDS on the h path.
//  - scales folded (r7): i/f/o weights * -L (sigmoid sign), g * +2L (tanh
//    form), cell kept in 2L-space.
// (Round 9 note: resubmission — Round 9 never acquired a GPU
// (GPUAcquisitionTimeout); no kernel evidence to update on.)
__global__ __launch_bounds__(64, 1)
void lstm_pipe_kernel(const float* __restrict__ x,
                      const float* __restrict__ Wx,
                      const float* __restrict__ Wh,
                      const float* __restrict__ bias,
                      const float* __restrict__ Wd,
                      const float* __restrict__ bd,
                      float* __restrict__ out) {
    const int b    = blockIdx.x;
    const int lane = threadIdx.x;
    const int lc   = (lane < HID) ? lane : (HID - 1);

    __shared__ __align__(16) float xs[TSTEPS + 8];

    // Stage x (coalesced float4 loads).
    const float4* xb4 = (const float4*)(x + (size_t)b * TSTEPS);
    float4* xs4 = (float4*)xs;
    #pragma unroll
    for (int i = lane; i < TSTEPS / 4; i += 64) xs4[i] = xb4[i];
    if (lane < 8) xs[TSTEPS + lane] = 0.0f;

    // Recurrent weights packed along k as half2 (25 pairs), scales folded:
    // i/f/o -> -L (sigmoid sign), g -> +2L (tanh form).
    const float SNEG = -LOG2E;
    const float S2L  = 2.0f * LOG2E;
    v2h wi[25], wf[25], wg[25], wo[25];
    #pragma unroll
    for (int k2 = 0; k2 < 25; ++k2) {
        const float* r0 = Wh + (2 * k2) * FOURH;
        const float* r1 = Wh + (2 * k2 + 1) * FOURH;
        wi[k2] = v2h{(_Float16)(SNEG * r0[lc]),           (_Float16)(SNEG * r1[lc])};
        wf[k2] = v2h{(_Float16)(SNEG * r0[HID + lc]),     (_Float16)(SNEG * r1[HID + lc])};
        wg[k2] = v2h{(_Float16)(S2L  * r0[2 * HID + lc]), (_Float16)(S2L  * r1[2 * HID + lc])};
        wo[k2] = v2h{(_Float16)(SNEG * r0[3 * HID + lc]), (_Float16)(SNEG * r1[3 * HID + lc])};
    }
    const float wx_i = SNEG * Wx[lc],           b_i = SNEG * bias[lc];
    const float wx_f = SNEG * Wx[HID + lc],     b_f = SNEG * bias[HID + lc];
    const float wx_g = S2L  * Wx[2 * HID + lc], b_g = S2L  * bias[2 * HID + lc];
    const float wx_o = SNEG * Wx[3 * HID + lc], b_o = SNEG * bias[3 * HID + lc];

    float cs = 0.0f;   // 2L-scaled cell state
    float h  = 0.0f;
    __syncthreads();   // x staging visible

    const float4* xsv = (const float4*)xs;
    float4 xq = xsv[0];

    for (int tb = 0; tb < TSTEPS; tb += 4) {
        const float4 xq_next = xsv[(tb >> 2) + 1];   // prefetch next block

        #pragma unroll
        for (int s = 0; s < 4; ++s) {
            const float xt = (s == 0) ? xq.x : (s == 1) ? xq.y
                           : (s == 2) ? xq.z : xq.w;

            // --- h broadcast: f16 + neighbor via DPP + pack + 25 readlane.
            const unsigned h16  = (unsigned)__builtin_bit_cast(unsigned short, (_Float16)h);
            const unsigned h16n = (unsigned)__builtin_amdgcn_update_dpp(
                0, (int)h16, 0x101 /*row_shl:1*/, 0xf, 0xf, true);
            const unsigned hp = h16 | (h16n << 16);
            unsigned sh[25];
            #pragma unroll
            for (int k = 0; k < 25; ++k)
                sh[k] = (unsigned)__builtin_amdgcn_readlane((int)hp, 2 * k);

            // --- gate i: dots, then activation (hides under g-dots).
            float ai0 = fmaf(xt, wx_i, b_i), ai1 = 0.f;
            #pragma unroll
            for (int j = 0; j < 12; ++j) {
                ai0 = __builtin_amdgcn_fdot2(wi[2 * j],     bc_v2h(sh[2 * j]),     ai0, false);
                ai1 = __builtin_amdgcn_fdot2(wi[2 * j + 1], bc_v2h(sh[2 * j + 1]), ai1, false);
            }
            ai0 = __builtin_amdgcn_fdot2(wi[24], bc_v2h(sh[24]), ai0, false);
            const float zi = ai0 + ai1;
            const float ig = frcp(1.0f + fexp2(zi));

            // --- gate g: dots, then gg2L and prod (hides under f-dots).
            float ag0 = fmaf(xt, wx_g, b_g), ag1 = 0.f;
            #pragma unroll
            for (int j = 0; j < 12; ++j) {
                ag0 = __builtin_amdgcn_fdot2(wg[2 * j],     bc_v2h(sh[2 * j]),     ag0, false);
                ag1 = __builtin_amdgcn_fdot2(wg[2 * j + 1], bc_v2h(sh[2 * j + 1]), ag1, false);
            }
            ag0 = __builtin_amdgcn_fdot2(wg[24], bc_v2h(sh[24]), ag0, false);
            const float zg = ag0 + ag1;
            const float sg = frcp(1.0f + fexp2(zg));
            const float gg2L = fmaf(-4.0f * LOG2E, sg, 2.0f * LOG2E); // 2L*tanh
            const float prod = ig * gg2L;

            // --- gate f: dots, then fg, cs, and start exp2(cs)/rcp under o-dots.
            float af0 = fmaf(xt, wx_f, b_f), af1 = 0.f;
            #pragma unroll
            for (int j = 0; j < 12; ++j) {
                af0 = __builtin_amdgcn_fdot2(wf[2 * j],     bc_v2h(sh[2 * j]),     af0, false);
                af1 = __builtin_amdgcn_fdot2(wf[2 * j + 1], bc_v2h(sh[2 * j + 1]), af1, false);
            }
            af0 = __builtin_amdgcn_fdot2(wf[24], bc_v2h(sh[24]), af0, false);
            const float zf = af0 + af1;
            const float fg = frcp(1.0f + fexp2(zf));
            const float cs_new = fmaf(fg, cs, prod);        // 2L * c
            const float Rc = frcp(1.0f + fexp2(cs_new));    // issues under o-dots

            // --- gate o: dots, then og and h.
            float ao0 = fmaf(xt, wx_o, b_o), ao1 = 0.f;
            #pragma unroll
            for (int j = 0; j < 12; ++j) {
                ao0 = __builtin_amdgcn_fdot2(wo[2 * j],     bc_v2h(sh[2 * j]),     ao0, false);
                ao1 = __builtin_amdgcn_fdot2(wo[2 * j + 1], bc_v2h(sh[2 * j + 1]), ao1, false);
            }
            ao0 = __builtin_amdgcn_fdot2(wo[24], bc_v2h(sh[24]), ao0, false);
            const float zo = ao0 + ao1;
            const float og = frcp(1.0f + fexp2(zo));

            cs = cs_new;
            const float tc = fmaf(-2.0f, Rc, 1.0f);         // tanh(c)
            h = og * tc;
        }

        xq = xq_next;
    }

    // out[b] = h_T . Wd + bd
    float v = (lane < HID) ? h * Wd[lane] : 0.0f;
    #pragma unroll
    for (int off = 32; off > 0; off >>= 1) v += __shfl_down(v, off);
    if (lane == 0) out[b] = v + bd[0];
}

extern "C" void kernel_launch(void* const* d_in, const int* in_sizes, int n_in,
                              void* d_out, int out_size, void* d_ws, size_t ws_size,
                              hipStream_t stream) {
    const float* x    = (const float*)d_in[0];  // [1024, 2048, 1]
    const float* Wx   = (const float*)d_in[1];  // [1, 200]
    const float* Wh   = (const float*)d_in[2];  // [50, 200]
    const float* bias = (const float*)d_in[3];  // [200]
    const float* Wd   = (const float*)d_in[4];  // [50, 1]
    const float* bd   = (const float*)d_in[5];  // [1]
    float* out = (float*)d_out;                 // [1024, 1]

    lstm_pipe_kernel<<<dim3(NBATCH), dim3(64), 0, stream>>>(
        x, Wx, Wh, bias, Wd, bd, out);
}

// Round 12
// 639.668 us; speedup vs baseline: 1.6732x; 1.0738x over previous
//
#include <hip/hip_runtime.h>

#define HID 50
#define FOURH 200
#define TSTEPS 2048
#define NBATCH 1024

#define LOG2E 1.44269504f

typedef _Float16 v2h __attribute__((ext_vector_type(2)));

__device__ __forceinline__ float frcp(float x)  { return __builtin_amdgcn_rcpf(x); }
__device__ __forceinline__ float fexp2(float x) { return __builtin_amdgcn_exp2f(x); }
__device__ __forceinline__ v2h bc_v2h(unsigned int u) {
    return __builtin_bit_cast(v2h, u);
}

// Issue model v3 (fits r0..r10 within ~3%): lone wave, dur = plainVALU*4cy +
// trans*16cy (+~0 idle). r10: 156*4 + 10*16 = 784 ~= 805 measured. Levers:
// every rcp/exp2 = 16cy, every plain inst = 4cy. This round:
//  - rcp MERGES: ig*gg2L = 2L(eg-1)/[(1+ei)(1+eg)] -> one rcp for two;
//    h = og*tanh(c) = (ec-1)/[(1+eo)(1+ec)] -> one rcp for two.
//    Trans 10 -> 8 (5 exp2 + 3 rcp). NaN-free: products <= ~1e24 << f32 max,
//    rcp underflows to 0 at the saturated tails (correct limits).
//  - SINGLE 25-dot chain per gate, init = fmaf(xt,wx,b): kills 4 movs + 4
//    z-adds. Compiler interleaves the 4 chains (16cy spacing >= dep latency).
//  - h broadcast: DPP row_shl:1 on f32 h, then ONE v_cvt_pkrtz_f16_f32 packs
//    (h, h_neighbor) -> 25 v_readlane -> SGPR fdot2 operands (r2 path).
//    RTZ quant of h: absmax ~2x (still 4x under threshold).
//  - scales folded: i/f/o weights * -L, g * +2L; cell in 2L-space (r7).
//  - x via float4, one LDS read / 4 steps, prefetched a block ahead (r10).
// (Round 11 fix: cvt_pkrtz returns __fp16-vector, distinct type from
// _Float16-vector v2h -> bit_cast the builtin's result directly.)
__global__ __launch_bounds__(64, 1)
void lstm_trans_kernel(const float* __restrict__ x,
                       const float* __restrict__ Wx,
                       const float* __restrict__ Wh,
                       const float* __restrict__ bias,
                       const float* __restrict__ Wd,
                       const float* __restrict__ bd,
                       float* __restrict__ out) {
    const int b    = blockIdx.x;
    const int lane = threadIdx.x;
    const int lc   = (lane < HID) ? lane : (HID - 1);

    __shared__ __align__(16) float xs[TSTEPS + 8];

    // Stage x (coalesced float4 loads).
    const float4* xb4 = (const float4*)(x + (size_t)b * TSTEPS);
    float4* xs4 = (float4*)xs;
    #pragma unroll
    for (int i = lane; i < TSTEPS / 4; i += 64) xs4[i] = xb4[i];
    if (lane < 8) xs[TSTEPS + lane] = 0.0f;

    // Recurrent weights packed along k as half2 (25 pairs), scales folded:
    // i/f/o -> -L (sigmoid sign), g -> +2L (tanh form).
    const float SNEG = -LOG2E;
    const float S2L  = 2.0f * LOG2E;
    v2h wi[25], wf[25], wg[25], wo[25];
    #pragma unroll
    for (int k2 = 0; k2 < 25; ++k2) {
        const float* r0 = Wh + (2 * k2) * FOURH;
        const float* r1 = Wh + (2 * k2 + 1) * FOURH;
        wi[k2] = v2h{(_Float16)(SNEG * r0[lc]),           (_Float16)(SNEG * r1[lc])};
        wf[k2] = v2h{(_Float16)(SNEG * r0[HID + lc]),     (_Float16)(SNEG * r1[HID + lc])};
        wg[k2] = v2h{(_Float16)(S2L  * r0[2 * HID + lc]), (_Float16)(S2L  * r1[2 * HID + lc])};
        wo[k2] = v2h{(_Float16)(SNEG * r0[3 * HID + lc]), (_Float16)(SNEG * r1[3 * HID + lc])};
    }
    const float wx_i = SNEG * Wx[lc],           b_i = SNEG * bias[lc];
    const float wx_f = SNEG * Wx[HID + lc],     b_f = SNEG * bias[HID + lc];
    const float wx_g = S2L  * Wx[2 * HID + lc], b_g = S2L  * bias[2 * HID + lc];
    const float wx_o = SNEG * Wx[3 * HID + lc], b_o = SNEG * bias[3 * HID + lc];

    float cs = 0.0f;   // 2L-scaled cell state
    float h  = 0.0f;
    __syncthreads();   // x staging visible

    const float4* xsv = (const float4*)xs;
    float4 xq = xsv[0];

    for (int tb = 0; tb < TSTEPS; tb += 4) {
        const float4 xq_next = xsv[(tb >> 2) + 1];   // prefetch next block

        #pragma unroll
        for (int s = 0; s < 4; ++s) {
            const float xt = (s == 0) ? xq.x : (s == 1) ? xq.y
                           : (s == 2) ? xq.z : xq.w;

            // --- h broadcast: DPP neighbor (f32) -> cvt_pkrtz pack -> 25 readlane.
            const int hi32 = __builtin_bit_cast(int, h);
            const int hn32 = __builtin_amdgcn_update_dpp(
                0, hi32, 0x101 /*row_shl:1*/, 0xf, 0xf, true);
            const float hn = __builtin_bit_cast(float, hn32);
            const unsigned hp =
                __builtin_bit_cast(unsigned, __builtin_amdgcn_cvt_pkrtz(h, hn));
            unsigned sh[25];
            #pragma unroll
            for (int k = 0; k < 25; ++k)
                sh[k] = (unsigned)__builtin_amdgcn_readlane((int)hp, 2 * k);

            // --- 4 single dot chains (25 fdot2 each), init = x-path + bias.
            float zi = fmaf(xt, wx_i, b_i);
            #pragma unroll
            for (int j = 0; j < 25; ++j)
                zi = __builtin_amdgcn_fdot2(wi[j], bc_v2h(sh[j]), zi, false);
            const float ei = fexp2(zi);                 // e^{-z_i}

            float zg = fmaf(xt, wx_g, b_g);
            #pragma unroll
            for (int j = 0; j < 25; ++j)
                zg = __builtin_amdgcn_fdot2(wg[j], bc_v2h(sh[j]), zg, false);
            const float eg = fexp2(zg);                 // e^{2 z_g}

            // prod = ig*gg2L = 2L(eg-1) / [(1+ei)(1+eg)]  (one rcp for both)
            const float den1 = (1.0f + ei) * (1.0f + eg);
            const float r1   = frcp(den1);
            const float num1 = fmaf(eg, S2L, -S2L);     // 2L*(eg-1)
            const float prod = num1 * r1;

            float zf = fmaf(xt, wx_f, b_f);
            #pragma unroll
            for (int j = 0; j < 25; ++j)
                zf = __builtin_amdgcn_fdot2(wf[j], bc_v2h(sh[j]), zf, false);
            const float ef = fexp2(zf);                 // e^{-z_f}
            const float fg = frcp(1.0f + ef);

            const float cs_new = fmaf(fg, cs, prod);    // 2L * c
            const float ec = fexp2(cs_new);             // e^{2c} (under o-dots)

            float zo = fmaf(xt, wx_o, b_o);
            #pragma unroll
            for (int j = 0; j < 25; ++j)
                zo = __builtin_amdgcn_fdot2(wo[j], bc_v2h(sh[j]), zo, false);
            const float eo = fexp2(zo);                 // e^{-z_o}

            // h = og * tanh(c) = (ec-1) / [(1+eo)(1+ec)]  (one rcp for both)
            const float den2 = (1.0f + eo) * (1.0f + ec);
            const float r2   = frcp(den2);
            const float num2 = ec - 1.0f;
            cs = cs_new;
            h  = num2 * r2;
        }

        xq = xq_next;
    }

    // out[b] = h_T . Wd + bd
    float v = (lane < HID) ? h * Wd[lane] : 0.0f;
    #pragma unroll
    for (int off = 32; off > 0; off >>= 1) v += __shfl_down(v, off);
    if (lane == 0) out[b] = v + bd[0];
}

extern "C" void kernel_launch(void* const* d_in, const int* in_sizes, int n_in,
                              void* d_out, int out_size, void* d_ws, size_t ws_size,
                              hipStream_t stream) {
    const float* x    = (const float*)d_in[0];  // [1024, 2048, 1]
    const float* Wx   = (const float*)d_in[1];  // [1, 200]
    const float* Wh   = (const float*)d_in[2];  // [50, 200]
    const float* bias = (const float*)d_in[3];  // [200]
    const float* Wd   = (const float*)d_in[4];  // [50, 1]
    const float* bd   = (const float*)d_in[5];  // [1]
    float* out = (float*)d_out;                 // [1024, 1]

    lstm_trans_kernel<<<dim3(NBATCH), dim3(64), 0, stream>>>(
        x, Wx, Wh, bias, Wd, bd, out);
}